// Round 7
// baseline (227.644 us; speedup 1.0000x reference)
//
#include <hip/hip_runtime.h>

// ArtNetwork: y = sigmoid(Wout @ tanh(W8 @ ... tanh(W1 @ tanh(Win@x+b)) ...))
// Design (R7): division-lean rational tanh on the MAIN pipe.
//  Calibrated HW model (R5/R6 counters): wave64 transcendental (v_exp/v_rcp_f32)
//  holds the SIMD issue port ~16 cyc; main VALU 2 cyc; costs ADD. R6 spent 70%
//  of busy cycles on 97 trans-ops/iter. Fix: tanh as minimax-adjusted Pade(5,4)
//    tanh(z) ~= z*(1 + a1*u + a2*u^2) / (1 + b1*u + b2*u^2),  u = z^2, |z|<=4
//  (continued-fraction 945/105/1 & 945/420/15 scaled, numerator u^2 coeff
//  nudged 1->0.98 to equioscillate: max err ~5.4e-4 on [-4,4]).
//  P,Q evaluated in PACKED f16 (v_pk_fma_f16 full-rate; __builtin_elementwise_fma
//  forces fusion); the 4 denominators reciprocated with ONE v_rcp_f32 product
//  tree in f32 (no sub-word extracts). 31 main + 1 trans per 4 tanh (=78 cyc)
//  vs R6's 15 main + 5 trans (=110 cyc).
//  - All layers as v_mfma_f32_16x16x16_f16; C/D layout == B layout, so
//    MFMA out -> tanh -> next B frag. No LDS, no shuffles in the loop.
//  - Input layer as MFMA: A=[Win | b | 0], B={x,y,1,*} (quad>0 B don't-care).
//  - Output: A=KOUT*Wout rows 0..2; sigmoid=1/(1+exp2(acco)) with one shared
//    rcp across 6 values (known-good R5 epilogue).
//  - 4096 blocks x 256 thr, launch_bounds(256,8); 2 tiles (32 pts)/wave-iter.

typedef float  f32x4 __attribute__((ext_vector_type(4)));
typedef __fp16 f16x4 __attribute__((ext_vector_type(4)));
typedef __fp16 f16x2 __attribute__((ext_vector_type(2)));

#define KOUT (-1.4426950408889634f) // -log2(e): exp2(KOUT*z) = e^{-z}

__device__ __forceinline__ f16x2 splat2(float v) {
    __fp16 h = (__fp16)v;
    f16x2 r = {h, h};
    return r;
}

// tanh of 4 values (f32 in, f16x4 B-frag out). Pade(5,4), |z|<=4.
__device__ __forceinline__ f16x4 pk_tanh4(f32x4 y) {
    const f16x2 A1 = splat2(0.11111111f);
    const f16x2 A2 = splat2(0.00103704f);   // 0.98/945
    const f16x2 B1 = splat2(0.44444444f);
    const f16x2 B2 = splat2(0.01587302f);
    const f16x2 ONE = splat2(1.0f);

    f16x2 z01 = __builtin_amdgcn_cvt_pkrtz(y[0], y[1]);
    f16x2 z23 = __builtin_amdgcn_cvt_pkrtz(y[2], y[3]);
    f16x2 u01 = z01 * z01;
    f16x2 u23 = z23 * z23;
    // n = z * (1 + u*(A1 + u*A2))
    f16x2 p01 = __builtin_elementwise_fma(u01, A2, A1);
    f16x2 p23 = __builtin_elementwise_fma(u23, A2, A1);
    p01 = __builtin_elementwise_fma(u01, p01, ONE);
    p23 = __builtin_elementwise_fma(u23, p23, ONE);
    f16x2 n01 = z01 * p01;
    f16x2 n23 = z23 * p23;
    // q = 1 + u*(B1 + u*B2)   (q in [1, 12.2])
    f16x2 q01 = __builtin_elementwise_fma(u01, B2, B1);
    f16x2 q23 = __builtin_elementwise_fma(u23, B2, B1);
    q01 = __builtin_elementwise_fma(u01, q01, ONE);
    q23 = __builtin_elementwise_fma(u23, q23, ONE);
    // one f32 rcp for all 4 denominators via product tree
    float d0 = (float)q01.x, d1 = (float)q01.y;
    float d2 = (float)q23.x, d3 = (float)q23.y;
    float m01 = d0 * d1, m23 = d2 * d3;         // <= 149 each
    float r   = __builtin_amdgcn_rcpf(m01 * m23);
    float i01 = r * m23, i23 = r * m01;         // 1/(d0 d1), 1/(d2 d3)
    float v0 = i01 * d1, v1 = i01 * d0;
    float v2 = i23 * d3, v3 = i23 * d2;         // 1/d_i
    f16x2 inv01 = __builtin_amdgcn_cvt_pkrtz(v0, v1);
    f16x2 inv23 = __builtin_amdgcn_cvt_pkrtz(v2, v3);
    f16x2 t01 = n01 * inv01;
    f16x2 t23 = n23 * inv23;
    return __builtin_shufflevector(t01, t23, 0, 1, 2, 3);
}

__global__ __launch_bounds__(256, 8)
void artnet_kernel(const float2* __restrict__ x,     // [N][2]
                   const float2* __restrict__ Win,   // [16][2]
                   const float*  __restrict__ bin,   // [16]
                   const float4* __restrict__ Wh,    // [8][16][16]
                   const float4* __restrict__ Wout,  // [3][16]
                   float* __restrict__ out,          // [N][3]
                   int nPairs, int nWaves)
{
    const int tid  = blockIdx.x * 256 + threadIdx.x;
    const int gw   = tid >> 6;            // global wave id
    const int lane = threadIdx.x & 63;
    const int row  = lane & 15;           // m / point-col index
    const int quad = lane >> 4;           // 0..3

    // ---- Hidden-layer A fragments: A[m=row][k=quad*4+j] = W[l][row][k]
    f16x4 aw[8];
#pragma unroll
    for (int l = 0; l < 8; ++l) {
        float4 w = Wh[l * 64 + row * 4 + quad];
        f16x2 lo = __builtin_amdgcn_cvt_pkrtz(w.x, w.y);
        f16x2 hi = __builtin_amdgcn_cvt_pkrtz(w.z, w.w);
        aw[l] = __builtin_shufflevector(lo, hi, 0, 1, 2, 3);
    }

    // ---- Input-layer A fragment: k=0 -> Win.x, k=1 -> Win.y, k=2 -> b
    f16x4 awin = {(__fp16)0.0f, (__fp16)0.0f, (__fp16)0.0f, (__fp16)0.0f};
    if (quad == 0) {
        float2 wr = Win[row];
        f16x2 lo = __builtin_amdgcn_cvt_pkrtz(wr.x, wr.y);
        f16x2 hi = __builtin_amdgcn_cvt_pkrtz(bin[row], 0.0f);
        awin = __builtin_shufflevector(lo, hi, 0, 1, 2, 3);
    }

    // ---- Output-layer A fragment: rows 0..2 = KOUT*Wout[row]
    f16x4 awo = {(__fp16)0.0f, (__fp16)0.0f, (__fp16)0.0f, (__fp16)0.0f};
    if (row < 3) {
        float4 w = Wout[row * 4 + quad];
        f16x2 lo = __builtin_amdgcn_cvt_pkrtz(w.x * KOUT, w.y * KOUT);
        f16x2 hi = __builtin_amdgcn_cvt_pkrtz(w.z * KOUT, w.w * KOUT);
        awo = __builtin_shufflevector(lo, hi, 0, 1, 2, 3);
    }

    const f32x4 zero4 = {0.0f, 0.0f, 0.0f, 0.0f};
    const f16x2 one0  = {(__fp16)1.0f, (__fp16)0.0f};

    for (int pi = gw; pi < nPairs; pi += nWaves) {
        const int t0 = pi * 2;           // first tile of the pair
        f16x4 bf[2];
        f32x4 acco[2];

        // ---- Input layer via MFMA: B = {x, y, 1, *}; quad>0 is don't-care.
#pragma unroll
        for (int s = 0; s < 2; ++s) {
            float2 xv = x[(t0 + s) * 16 + row];
            f16x2 lo = __builtin_amdgcn_cvt_pkrtz(xv.x, xv.y);
            bf[s] = __builtin_shufflevector(lo, one0, 0, 1, 2, 3);
        }
#pragma unroll
        for (int s = 0; s < 2; ++s) {
            f32x4 acc = __builtin_amdgcn_mfma_f32_16x16x16f16(awin, bf[s], zero4, 0, 0, 0);
            bf[s] = pk_tanh4(acc);
        }

        // ---- 8 hidden layers: MFMA -> packed Pade tanh -> next B frag
#pragma unroll
        for (int l = 0; l < 8; ++l) {
#pragma unroll
            for (int s = 0; s < 2; ++s) {
                f32x4 acc = __builtin_amdgcn_mfma_f32_16x16x16f16(aw[l], bf[s], zero4, 0, 0, 0);
                bf[s] = pk_tanh4(acc);
            }
        }

        // ---- Output MFMA: quad-0 lanes hold KOUT*zout in acc[0..2]
#pragma unroll
        for (int s = 0; s < 2; ++s)
            acco[s] = __builtin_amdgcn_mfma_f32_16x16x16f16(awo, bf[s], zero4, 0, 0, 0);

        // ---- Sigmoid epilogue: one rcp across 6 values (2 tiles x 3 channels)
        if (quad == 0) {
            float ea0 = __builtin_amdgcn_exp2f(acco[0][0]);
            float ea1 = __builtin_amdgcn_exp2f(acco[0][1]);
            float ea2 = __builtin_amdgcn_exp2f(acco[0][2]);
            float eb0 = __builtin_amdgcn_exp2f(acco[1][0]);
            float eb1 = __builtin_amdgcn_exp2f(acco[1][1]);
            float eb2 = __builtin_amdgcn_exp2f(acco[1][2]);
            float da0 = ea0 + 1.0f, da1 = ea1 + 1.0f, da2 = ea2 + 1.0f;
            float db0 = eb0 + 1.0f, db1 = eb1 + 1.0f, db2 = eb2 + 1.0f;
            float pa01 = da0 * da1, P3a = pa01 * da2;   // d <= 56: P6 <= 3.1e10
            float pb01 = db0 * db1, P3b = pb01 * db2;
            float r  = __builtin_amdgcn_rcpf(P3a * P3b);
            float rA = r * P3b, rB = r * P3a;           // 1/P3a, 1/P3b
            float sa2 = rA * pa01;                      // 1/da2
            float ia  = rA * da2;                       // 1/(da0*da1)
            float sa0 = ia * da1, sa1 = ia * da0;
            float sb2 = rB * pb01;
            float ib  = rB * db2;
            float sb0 = ib * db1, sb1 = ib * db0;
            const int p0 = t0 * 16 + row;
            out[p0 * 3 + 0] = sa0;
            out[p0 * 3 + 1] = sa1;
            out[p0 * 3 + 2] = sa2;
            const int p1 = p0 + 16;
            out[p1 * 3 + 0] = sb0;
            out[p1 * 3 + 1] = sb1;
            out[p1 * 3 + 2] = sb2;
        }
    }
}

extern "C" void kernel_launch(void* const* d_in, const int* in_sizes, int n_in,
                              void* d_out, int out_size, void* d_ws, size_t ws_size,
                              hipStream_t stream) {
    const float2* x    = (const float2*)d_in[0];
    const float2* Win  = (const float2*)d_in[1];
    const float*  bin  = (const float*) d_in[2];
    const float4* Wh   = (const float4*)d_in[3];
    const float4* Wout = (const float4*)d_in[4];
    float* out = (float*)d_out;

    const int n      = in_sizes[0] / 2;   // 4,194,304 points
    const int nPairs = n / 32;            // 2 tiles of 16 points per wave-iter
    const int blocks = 4096;              // 16384 waves, 8 iters/wave, no tail
    const int nWaves = blocks * 4;

    artnet_kernel<<<blocks, 256, 0, stream>>>(x, Win, bin, Wh, Wout, out, nPairs, nWaves);
}

// Round 8
// 210.983 us; speedup vs baseline: 1.0790x; 1.0790x over previous
//
#include <hip/hip_runtime.h>

// ArtNetwork: y = sigmoid(Wout @ tanh(W8 @ ... tanh(W1 @ tanh(Win@x+b)) ...))
// Design (R8): scalar-f32 Pade(5,4) tanh + 8-wide shared-rcp product tree.
//  Calibrated model (validated on R6 within 0.2%): main VALU op = 2 cyc/wave,
//  transcendental (v_exp/v_rcp_f32) = 16 cyc/wave, costs add on the issue port.
//  R3/R7 showed f16x2 vector arithmetic bloats ~2x vs its static count -> all
//  activation math here is SCALAR f32 (proven 1:1 lowering), MFMA frags f16.
//  tanh(z) ~= z*(945 + 105u + 0.98u^2)/(945 + 420u + 15u^2)/945-normalized,
//  u=z^2, |z|<=4 guaranteed (16 inputs x |w|<=0.25 x |h|<=1); max err ~5.4e-4.
//  Per layer (2 tiles = 8 values): 81 main + 1 rcp vs R6's 30 main + 10 trans.
//  - All layers as v_mfma_f32_16x16x16_f16; C/D layout == B layout, so
//    MFMA out -> tanh8 -> next B frags. No LDS, no shuffles in the loop.
//  - Input layer as MFMA: A=[Win | b | 0], B={x,y,1,*} (quad>0 B don't-care).
//  - Output: A=KOUT*Wout rows 0..2; sigmoid=1/(1+exp2(acco)), one rcp/6 values.
//  - 4096 blocks x 256 thr, launch_bounds(256,6); 2 tiles (32 pts)/wave-iter.

typedef float  f32x4 __attribute__((ext_vector_type(4)));
typedef __fp16 f16x4 __attribute__((ext_vector_type(4)));
typedef __fp16 f16x2 __attribute__((ext_vector_type(2)));

#define KOUT (-1.4426950408889634f) // -log2(e): exp2(KOUT*z) = e^{-z}

// Pade(5,4) coefficients (normalized by 945), numerator u^2 term minimax-nudged.
#define PA1 0.11111111f    // 105/945
#define PA2 0.00103704f    // 0.98/945
#define PB1 0.44444444f    // 420/945
#define PB2 0.01587302f    // 15/945

// tanh of 8 values (two f32x4 accs in, two f16x4 B-frags out), scalar f32,
// ONE v_rcp_f32 via 8-leaf product tree.
__device__ __forceinline__ void tanh8(f32x4 ya, f32x4 yb, f16x4* oa, f16x4* ob) {
    float z[8], n[8], q[8];
#pragma unroll
    for (int i = 0; i < 4; ++i) { z[i] = ya[i]; z[4 + i] = yb[i]; }
#pragma unroll
    for (int i = 0; i < 8; ++i) {
        float u = z[i] * z[i];
        float p = __builtin_fmaf(u, PA2, PA1);
        p = __builtin_fmaf(u, p, 1.0f);
        n[i] = z[i] * p;
        float t = __builtin_fmaf(u, PB2, PB1);
        q[i] = __builtin_fmaf(u, t, 1.0f);      // q in [1, 12.2]
    }
    float m01 = q[0] * q[1], m23 = q[2] * q[3];
    float m45 = q[4] * q[5], m67 = q[6] * q[7];
    float mA  = m01 * m23,   mB  = m45 * m67;    // <= 2.2e4
    float r   = __builtin_amdgcn_rcpf(mA * mB);  // M <= 4.8e8, fits f32
    float iA  = r * mB,      iB  = r * mA;       // 1/(q0..q3), 1/(q4..q7)
    float i01 = iA * m23,    i23 = iA * m01;
    float i45 = iB * m67,    i67 = iB * m45;
    float v0 = i01 * q[1], v1 = i01 * q[0];
    float v2 = i23 * q[3], v3 = i23 * q[2];
    float v4 = i45 * q[5], v5 = i45 * q[4];
    float v6 = i67 * q[7], v7 = i67 * q[6];
    f16x2 a01 = __builtin_amdgcn_cvt_pkrtz(n[0] * v0, n[1] * v1);
    f16x2 a23 = __builtin_amdgcn_cvt_pkrtz(n[2] * v2, n[3] * v3);
    f16x2 b01 = __builtin_amdgcn_cvt_pkrtz(n[4] * v4, n[5] * v5);
    f16x2 b23 = __builtin_amdgcn_cvt_pkrtz(n[6] * v6, n[7] * v7);
    *oa = __builtin_shufflevector(a01, a23, 0, 1, 2, 3);
    *ob = __builtin_shufflevector(b01, b23, 0, 1, 2, 3);
}

__global__ __launch_bounds__(256, 6)
void artnet_kernel(const float2* __restrict__ x,     // [N][2]
                   const float2* __restrict__ Win,   // [16][2]
                   const float*  __restrict__ bin,   // [16]
                   const float4* __restrict__ Wh,    // [8][16][16]
                   const float4* __restrict__ Wout,  // [3][16]
                   float* __restrict__ out,          // [N][3]
                   int nPairs, int nWaves)
{
    const int tid  = blockIdx.x * 256 + threadIdx.x;
    const int gw   = tid >> 6;            // global wave id
    const int lane = threadIdx.x & 63;
    const int row  = lane & 15;           // m / point-col index
    const int quad = lane >> 4;           // 0..3

    // ---- Hidden-layer A fragments: A[m=row][k=quad*4+j] = W[l][row][k]
    f16x4 aw[8];
#pragma unroll
    for (int l = 0; l < 8; ++l) {
        float4 w = Wh[l * 64 + row * 4 + quad];
        f16x2 lo = __builtin_amdgcn_cvt_pkrtz(w.x, w.y);
        f16x2 hi = __builtin_amdgcn_cvt_pkrtz(w.z, w.w);
        aw[l] = __builtin_shufflevector(lo, hi, 0, 1, 2, 3);
    }

    // ---- Input-layer A fragment: k=0 -> Win.x, k=1 -> Win.y, k=2 -> b
    f16x4 awin = {(__fp16)0.0f, (__fp16)0.0f, (__fp16)0.0f, (__fp16)0.0f};
    if (quad == 0) {
        float2 wr = Win[row];
        f16x2 lo = __builtin_amdgcn_cvt_pkrtz(wr.x, wr.y);
        f16x2 hi = __builtin_amdgcn_cvt_pkrtz(bin[row], 0.0f);
        awin = __builtin_shufflevector(lo, hi, 0, 1, 2, 3);
    }

    // ---- Output-layer A fragment: rows 0..2 = KOUT*Wout[row]
    f16x4 awo = {(__fp16)0.0f, (__fp16)0.0f, (__fp16)0.0f, (__fp16)0.0f};
    if (row < 3) {
        float4 w = Wout[row * 4 + quad];
        f16x2 lo = __builtin_amdgcn_cvt_pkrtz(w.x * KOUT, w.y * KOUT);
        f16x2 hi = __builtin_amdgcn_cvt_pkrtz(w.z * KOUT, w.w * KOUT);
        awo = __builtin_shufflevector(lo, hi, 0, 1, 2, 3);
    }

    const f32x4 zero4 = {0.0f, 0.0f, 0.0f, 0.0f};
    const f16x2 one0  = {(__fp16)1.0f, (__fp16)0.0f};

    for (int pi = gw; pi < nPairs; pi += nWaves) {
        const int t0 = pi * 2;           // first tile of the pair
        f16x4 bf[2];
        f32x4 acco[2];

        // ---- Input layer via MFMA: B = {x, y, 1, *}; quad>0 is don't-care.
#pragma unroll
        for (int s = 0; s < 2; ++s) {
            float2 xv = x[(t0 + s) * 16 + row];
            f16x2 lo = __builtin_amdgcn_cvt_pkrtz(xv.x, xv.y);
            bf[s] = __builtin_shufflevector(lo, one0, 0, 1, 2, 3);
        }
        {
            f32x4 a0 = __builtin_amdgcn_mfma_f32_16x16x16f16(awin, bf[0], zero4, 0, 0, 0);
            f32x4 a1 = __builtin_amdgcn_mfma_f32_16x16x16f16(awin, bf[1], zero4, 0, 0, 0);
            tanh8(a0, a1, &bf[0], &bf[1]);
        }

        // ---- 8 hidden layers: 2 MFMA -> tanh8 (one rcp) -> next B frags
#pragma unroll
        for (int l = 0; l < 8; ++l) {
            f32x4 a0 = __builtin_amdgcn_mfma_f32_16x16x16f16(aw[l], bf[0], zero4, 0, 0, 0);
            f32x4 a1 = __builtin_amdgcn_mfma_f32_16x16x16f16(aw[l], bf[1], zero4, 0, 0, 0);
            tanh8(a0, a1, &bf[0], &bf[1]);
        }

        // ---- Output MFMA: quad-0 lanes hold KOUT*zout in acc[0..2]
#pragma unroll
        for (int s = 0; s < 2; ++s)
            acco[s] = __builtin_amdgcn_mfma_f32_16x16x16f16(awo, bf[s], zero4, 0, 0, 0);

        // ---- Sigmoid epilogue: one rcp across 6 values (2 tiles x 3 channels)
        if (quad == 0) {
            float ea0 = __builtin_amdgcn_exp2f(acco[0][0]);
            float ea1 = __builtin_amdgcn_exp2f(acco[0][1]);
            float ea2 = __builtin_amdgcn_exp2f(acco[0][2]);
            float eb0 = __builtin_amdgcn_exp2f(acco[1][0]);
            float eb1 = __builtin_amdgcn_exp2f(acco[1][1]);
            float eb2 = __builtin_amdgcn_exp2f(acco[1][2]);
            float da0 = ea0 + 1.0f, da1 = ea1 + 1.0f, da2 = ea2 + 1.0f;
            float db0 = eb0 + 1.0f, db1 = eb1 + 1.0f, db2 = eb2 + 1.0f;
            float pa01 = da0 * da1, P3a = pa01 * da2;   // d <= 56: P6 <= 3.1e10
            float pb01 = db0 * db1, P3b = pb01 * db2;
            float r  = __builtin_amdgcn_rcpf(P3a * P3b);
            float rA = r * P3b, rB = r * P3a;           // 1/P3a, 1/P3b
            float sa2 = rA * pa01;                      // 1/da2
            float ia  = rA * da2;                       // 1/(da0*da1)
            float sa0 = ia * da1, sa1 = ia * da0;
            float sb2 = rB * pb01;
            float ib  = rB * db2;
            float sb0 = ib * db1, sb1 = ib * db0;
            const int p0 = t0 * 16 + row;
            out[p0 * 3 + 0] = sa0;
            out[p0 * 3 + 1] = sa1;
            out[p0 * 3 + 2] = sa2;
            const int p1 = p0 + 16;
            out[p1 * 3 + 0] = sb0;
            out[p1 * 3 + 1] = sb1;
            out[p1 * 3 + 2] = sb2;
        }
    }
}

extern "C" void kernel_launch(void* const* d_in, const int* in_sizes, int n_in,
                              void* d_out, int out_size, void* d_ws, size_t ws_size,
                              hipStream_t stream) {
    const float2* x    = (const float2*)d_in[0];
    const float2* Win  = (const float2*)d_in[1];
    const float*  bin  = (const float*) d_in[2];
    const float4* Wh   = (const float4*)d_in[3];
    const float4* Wout = (const float4*)d_in[4];
    float* out = (float*)d_out;

    const int n      = in_sizes[0] / 2;   // 4,194,304 points
    const int nPairs = n / 32;            // 2 tiles of 16 points per wave-iter
    const int blocks = 4096;              // 16384 waves, 8 iters/wave, no tail
    const int nWaves = blocks * 4;

    artnet_kernel<<<blocks, 256, 0, stream>>>(x, Win, bin, Wh, Wout, out, nPairs, nWaves);
}